// Round 4
// baseline (51.890 us; speedup 1.0000x reference)
//
#include <hip/hip_runtime.h>
#include <math.h>

// PAM module: B=8, C=64, CQ=8, N=2048
// out[b,c,i] = gamma * sum_j softmax_j(q[i,:]·k[:,j]) * v[c,j] + x[b,c,i]

#define NB  8
#define NC  64
#define NN  2048
#define L2E 1.44269504088896340736f
#define SPP 72          // sP pitch (ushorts) per 16-row: 144B rows, 2-way max
#define THR 8.0f        // defer-max threshold (exp2 domain)

typedef float f32x4 __attribute__((ext_vector_type(4)));
typedef __bf16 bf16x8 __attribute__((ext_vector_type(8)));
typedef __bf16 bf16x4 __attribute__((ext_vector_type(4)));
typedef unsigned short ushort_t;
typedef unsigned short us8 __attribute__((ext_vector_type(8)));

__device__ __forceinline__ unsigned short f2bf(float f) {
    unsigned u = __float_as_uint(f);
    u += 0x7fffu + ((u >> 16) & 1u);          // RNE
    return (unsigned short)(u >> 16);
}
__device__ __forceinline__ float bf2f(unsigned short h) {
    return __uint_as_float(((unsigned)h) << 16);
}

// ---------------- QKV projection (prep folded in) ----------------
// 512 blocks x 256 threads; block = 32 pixels of one batch; 8 channel-groups
// per pixel: sg0=q(8), sg1=k(8), sg2..5=v(12 each), sg6..7=v(8 each).
// Weights transposed into LDS once per block; compute reads are broadcasts.
__global__ __launch_bounds__(256) void qkv_kernel(
    const float* __restrict__ x,
    const float* __restrict__ Wq, const float* __restrict__ bq,
    const float* __restrict__ Wk, const float* __restrict__ bk,
    const float* __restrict__ Wv, const float* __restrict__ bv,
    ushort_t* __restrict__ Qws, ushort_t* __restrict__ Kws,
    ushort_t* __restrict__ Vws)
{
    __shared__ float sW[64][84];   // [c][o]: o 0-7 q*L2E, 8-15 k, 16-79 v
    __shared__ float sB[88];
    __shared__ float sX[32][68];   // [pixel][channel]

    const int tid = threadIdx.x;
    const int b  = blockIdx.x >> 6;
    const int n0 = (blockIdx.x & 63) * 32;

    for (int idx = tid; idx < 5120; idx += 256) {
        const int o = idx >> 6, c = idx & 63;
        float w;
        if (o < 8)       w = Wq[o * NC + c] * L2E;
        else if (o < 16) w = Wk[(o - 8) * NC + c];
        else             w = Wv[(o - 16) * NC + c];
        sW[c][o] = w;
    }
    if (tid < 88) {
        float v = 0.f;
        if (tid < 8)       v = bq[tid] * L2E;
        else if (tid < 16) v = bk[tid - 8];
        else if (tid < 80) v = bv[tid - 16];
        sB[tid] = v;
    }
    {
        const float* xg = x + (size_t)b * NC * NN + n0;
        for (int it = tid; it < 2048; it += 256) {
            const int c = it >> 5, nl = it & 31;
            sX[nl][c] = xg[(size_t)c * NN + nl];
        }
    }
    __syncthreads();

    const int nl = tid & 31;
    const int sg = tid >> 5;
    const int obase = (sg < 2) ? sg * 8
                    : (sg < 6) ? 16 + (sg - 2) * 12
                               : 64 + (sg - 6) * 8;
    const int cnt = (sg >= 2 && sg < 6) ? 12 : 8;

    float acc[12];
    #pragma unroll
    for (int j = 0; j < 12; j++) acc[j] = sB[obase + j];

    #pragma unroll
    for (int c4 = 0; c4 < 16; c4++) {
        const f32x4 xv4 = *(const f32x4*)&sX[nl][c4 * 4];
        #pragma unroll
        for (int e = 0; e < 4; e++) {
            const float xv = xv4[e];
            const float* wr = &sW[c4 * 4 + e][obase];
            #pragma unroll
            for (int j4 = 0; j4 < 3; j4++) {
                const f32x4 w = *(const f32x4*)(wr + j4 * 4);
                acc[j4*4+0] = fmaf(w[0], xv, acc[j4*4+0]);
                acc[j4*4+1] = fmaf(w[1], xv, acc[j4*4+1]);
                acc[j4*4+2] = fmaf(w[2], xv, acc[j4*4+2]);
                acc[j4*4+3] = fmaf(w[3], xv, acc[j4*4+3]);
            }
        }
    }

    const int n = n0 + nl;
    if (sg == 0) {
        us8 hi, lo;
        #pragma unroll
        for (int o = 0; o < 8; o++) {
            const unsigned short h = f2bf(acc[o]);
            hi[o] = h; lo[o] = f2bf(acc[o] - bf2f(h));
        }
        ushort_t* qo = Qws + ((size_t)b * NN + n) * 16;
        *(us8*)qo = hi; *(us8*)(qo + 8) = lo;
    } else if (sg == 1) {
        us8 hi, lo;
        #pragma unroll
        for (int o = 0; o < 8; o++) {
            const unsigned short h = f2bf(acc[o]);
            hi[o] = h; lo[o] = f2bf(acc[o] - bf2f(h));
        }
        ushort_t* ko = Kws + ((size_t)b * NN + n) * 16;
        *(us8*)ko = hi; *(us8*)(ko + 8) = lo;
    } else {
        const int vbase = obase - 16;
        #pragma unroll
        for (int j = 0; j < 12; j++)
            if (j < cnt)
                Vws[((size_t)b * NC + vbase + j) * NN + n] = f2bf(acc[j]);
    }
}

// ---------------- fused flash attention (MFMA, barrier-free loop) ----------
// 512 blocks (8b x 64rb) x 512 threads = 8 waves = 2 row-groups x 4 j-quarters.
// K,V direct from global (L2); P via per-wave LDS; defer-max softmax with
// per-lane deferred l; 4-way merge in LDS at the end.
__global__ __launch_bounds__(512, 4) void attn_kernel(
    const ushort_t* __restrict__ Qg, const ushort_t* __restrict__ Kg,
    const ushort_t* __restrict__ Vg, const float* __restrict__ x,
    const float* __restrict__ gamma, float* __restrict__ out)
{
    __shared__ __align__(16) char smem[30720];
    ushort_t* sP = (ushort_t*)smem;      // [8 waves][16 rows][SPP]
    float*    sM = (float*)smem;         // merge: [6][64][20]

    const int tid  = threadIdx.x;
    const int w    = tid >> 6;
    const int rg   = w >> 2;             // row-group 0..1
    const int jq   = w & 3;              // j-quarter 0..3
    const int lane = tid & 63;
    const int li   = lane & 15;
    const int g    = lane >> 4;
    const int b    = blockIdx.x >> 6;
    const int rb   = blockIdx.x & 63;
    const int i    = rb * 32 + rg * 16 + li;
    const int jbase = jq * 512;

    const ushort_t* Kb = Kg + (size_t)b * NN * 16;
    const ushort_t* Vb = Vg + (size_t)b * NC * NN;
    const bf16x8 qfrag = *(const bf16x8*)(Qg + ((size_t)b * NN + i) * 16 + (g & 1) * 8);
    ushort_t* sPw = sP + (w * 16 + li) * SPP;

    float m = -INFINITY, l = 0.f;
    f32x4 acc[4];
    #pragma unroll
    for (int cb = 0; cb < 4; cb++) acc[cb] = (f32x4){0.f, 0.f, 0.f, 0.f};
    const f32x4 zero4 = {0.f, 0.f, 0.f, 0.f};

    bf16x8 kc[4];
    #pragma unroll
    for (int f = 0; f < 4; f++)
        kc[f] = *(const bf16x8*)(Kb + (size_t)(jbase + f * 16 + li) * 16 + (g >> 1) * 8);

    #pragma unroll
    for (int t = 0; t < 8; t++) {
        const int j0 = jbase + t * 64;

        // V fragments for this step (consumed at step end -> latency hidden)
        bf16x8 vc[8];
        #pragma unroll
        for (int cb = 0; cb < 4; cb++) {
            #pragma unroll
            for (int jc = 0; jc < 2; jc++)
                vc[cb*2+jc] = *(const bf16x8*)(Vb + (size_t)(cb*16 + li) * NN
                                               + j0 + jc*32 + g*8);
        }

        // energies: exact fp32 dot via hi/lo cross terms, exp2 domain
        f32x4 e[4];
        #pragma unroll
        for (int f = 0; f < 4; f++)
            e[f] = __builtin_amdgcn_mfma_f32_16x16x32_bf16(kc[f], qfrag, zero4, 0, 0, 0);

        // prefetch next step's K into the (now consumed) kc regs
        if (t < 7) {
            #pragma unroll
            for (int f = 0; f < 4; f++)
                kc[f] = *(const bf16x8*)(Kb + (size_t)(jbase + (t+1)*64 + f*16 + li) * 16
                                         + (g >> 1) * 8);
        }

        // defer-max: common path has no cross-lane ops and no rescale
        float pmax = fmaxf(fmaxf(fmaxf(e[0][0], e[0][1]), fmaxf(e[0][2], e[0][3])),
                     fmaxf(fmaxf(fmaxf(e[1][0], e[1][1]), fmaxf(e[1][2], e[1][3])),
                     fmaxf(fmaxf(fmaxf(e[2][0], e[2][1]), fmaxf(e[2][2], e[2][3])),
                           fmaxf(fmaxf(e[3][0], e[3][1]), fmaxf(e[3][2], e[3][3])))));
        if (!__all(pmax <= m + THR)) {
            float mx = pmax;
            mx = fmaxf(mx, __shfl_xor(mx, 16));
            mx = fmaxf(mx, __shfl_xor(mx, 32));
            const float nm = fmaxf(m, mx);
            const float sc = __builtin_amdgcn_exp2f(m - nm);   // 0 on first step
            m = nm;
            l *= sc;
            #pragma unroll
            for (int cb = 0; cb < 4; cb++) {
                acc[cb][0] *= sc; acc[cb][1] *= sc;
                acc[cb][2] *= sc; acc[cb][3] *= sc;
            }
        }

        #pragma unroll
        for (int f = 0; f < 4; f++) {
            const float p0 = __builtin_amdgcn_exp2f(e[f][0] - m);
            const float p1 = __builtin_amdgcn_exp2f(e[f][1] - m);
            const float p2 = __builtin_amdgcn_exp2f(e[f][2] - m);
            const float p3 = __builtin_amdgcn_exp2f(e[f][3] - m);
            l += (p0 + p1) + (p2 + p3);            // per-lane partial
            const bf16x4 pk = { (__bf16)p0, (__bf16)p1, (__bf16)p2, (__bf16)p3 };
            *(bf16x4*)(sPw + f * 16 + g * 4) = pk; // same-wave LDS, no barrier
        }

        #pragma unroll
        for (int jc = 0; jc < 2; jc++) {
            const bf16x8 pf = *(const bf16x8*)(sPw + jc * 32 + g * 8);
            #pragma unroll
            for (int cb = 0; cb < 4; cb++)
                acc[cb] = __builtin_amdgcn_mfma_f32_16x16x32_bf16(vc[cb*2+jc], pf, acc[cb], 0, 0, 0);
        }
    }

    // ---- 4-way j-quarter merge ----
    __syncthreads();
    if (jq != 0) {
        float* mp = sM + ((size_t)(rg * 3 + (jq - 1)) * 64 + lane) * 20;
        #pragma unroll
        for (int cb = 0; cb < 4; cb++) *(f32x4*)(mp + cb * 4) = acc[cb];
        mp[16] = m; mp[17] = l;
    }
    __syncthreads();
    if (jq == 0) {
        const float* mp0 = sM + ((size_t)(rg * 3 + 0) * 64 + lane) * 20;
        const float* mp1 = sM + ((size_t)(rg * 3 + 1) * 64 + lane) * 20;
        const float* mp2 = sM + ((size_t)(rg * 3 + 2) * 64 + lane) * 20;
        const float m0 = mp0[16], m1 = mp1[16], m2 = mp2[16];
        const float M  = fmaxf(fmaxf(m, m0), fmaxf(m1, m2));
        const float s  = __builtin_amdgcn_exp2f(m  - M);
        const float s0 = __builtin_amdgcn_exp2f(m0 - M);
        const float s1 = __builtin_amdgcn_exp2f(m1 - M);
        const float s2 = __builtin_amdgcn_exp2f(m2 - M);
        float lt = l * s + mp0[17] * s0 + mp1[17] * s1 + mp2[17] * s2;
        lt += __shfl_xor(lt, 16);
        lt += __shfl_xor(lt, 32);
        const float inv = 1.0f / lt;
        const float gmv = gamma[0];
        const size_t base = (size_t)b * NC * NN + i;
        #pragma unroll
        for (int cb = 0; cb < 4; cb++) {
            const f32x4 a0 = *(const f32x4*)(mp0 + cb * 4);
            const f32x4 a1 = *(const f32x4*)(mp1 + cb * 4);
            const f32x4 a2 = *(const f32x4*)(mp2 + cb * 4);
            #pragma unroll
            for (int q = 0; q < 4; q++) {
                const float a = (acc[cb][q] * s + a0[q] * s0 + a1[q] * s1 + a2[q] * s2) * inv;
                const size_t idx = base + (size_t)(cb * 16 + g * 4 + q) * NN;
                out[idx] = fmaf(gmv, a, x[idx]);
            }
        }
    }
}

extern "C" void kernel_launch(void* const* d_in, const int* in_sizes, int n_in,
                              void* d_out, int out_size, void* d_ws, size_t ws_size,
                              hipStream_t stream) {
    const float* x     = (const float*)d_in[0];
    const float* Wq    = (const float*)d_in[1];
    const float* bq    = (const float*)d_in[2];
    const float* Wk    = (const float*)d_in[3];
    const float* bk    = (const float*)d_in[4];
    const float* Wv    = (const float*)d_in[5];
    const float* bv    = (const float*)d_in[6];
    const float* gamma = (const float*)d_in[7];
    float* out = (float*)d_out;

    // ws (ushorts): Q [8][2048][16] | K [8][2048][16] | V [8][64][2048] = 3 MB
    ushort_t* Qws = (ushort_t*)d_ws;
    ushort_t* Kws = Qws + (size_t)NB * NN * 16;
    ushort_t* Vws = Kws + (size_t)NB * NN * 16;

    qkv_kernel<<<NB * 64, 256, 0, stream>>>(x, Wq, bq, Wk, bk, Wv, bv, Qws, Kws, Vws);
    attn_kernel<<<NB * 64, 512, 0, stream>>>(Qws, Kws, Vws, x, gamma, out);
}